// Round 1
// baseline (288.770 us; speedup 1.0000x reference)
//
#include <hip/hip_runtime.h>
#include <hip/hip_bf16.h>

#define DIMD 1024
#define HIDD 128
#define SEQ  8192
#define BATCH 4
#define KEEP 1024
#define BM 64
#define KB 64

__device__ __forceinline__ float gelu_exact(float h) {
    return 0.5f * h * (1.0f + erff(h * 0.70710678118654752440f));
}

// ---------------- Kernel 1: fused scorer (x@W1 + b1 -> gelu -> @W2 + b2) ----
__global__ __launch_bounds__(256, 2)
void score_kernel(const float* __restrict__ x, const float* __restrict__ W1,
                  const float* __restrict__ b1, const float* __restrict__ W2,
                  const float* __restrict__ b2, float* __restrict__ scores) {
    __shared__ float xs[BM][KB + 4];   // +4 pad keeps float4 alignment, breaks bank stride
    __shared__ float ws[KB][HIDD];

    const int tid = threadIdx.x;
    const int tx = tid & 15;    // 16 col groups
    const int ty = tid >> 4;    // 16 row groups (4 rows each)
    const long rowBase = (long)blockIdx.x * BM;

    float acc[4][8];
#pragma unroll
    for (int i = 0; i < 4; ++i)
#pragma unroll
        for (int j = 0; j < 8; ++j) acc[i][j] = 0.0f;

    for (int kt = 0; kt < DIMD; kt += KB) {
        __syncthreads();  // protect LDS reads of previous chunk
        {   // stage x tile: row-major [64][KB], 64B-chunk coalesced
            const int row = tid >> 2, q = tid & 3;
            const float* gx = x + (rowBase + row) * DIMD + kt;
#pragma unroll
            for (int j = 0; j < 4; ++j) {
                const int kl = (q + j * 4) * 4;
                float4 v = *(const float4*)(gx + kl);
                *(float4*)&xs[row][kl] = v;
            }
        }
        {   // stage W1 tile: flat contiguous copy (KB*HIDD floats)
            const float4* gw = (const float4*)(W1 + (long)kt * HIDD);
            float4* lw = (float4*)&ws[0][0];
#pragma unroll
            for (int j = 0; j < 8; ++j) lw[j * 256 + tid] = gw[j * 256 + tid];
        }
        __syncthreads();

#pragma unroll 4
        for (int k = 0; k < KB; ++k) {
            const float4 w0 = *(const float4*)&ws[k][tx * 4];
            const float4 w1v = *(const float4*)&ws[k][64 + tx * 4];
#pragma unroll
            for (int i = 0; i < 4; ++i) {
                const float xv = xs[ty * 4 + i][k];
                acc[i][0] += xv * w0.x;  acc[i][1] += xv * w0.y;
                acc[i][2] += xv * w0.z;  acc[i][3] += xv * w0.w;
                acc[i][4] += xv * w1v.x; acc[i][5] += xv * w1v.y;
                acc[i][6] += xv * w1v.z; acc[i][7] += xv * w1v.w;
            }
        }
    }

    // epilogue: bias + exact gelu + W2 dot, reduce over tx (16 lanes)
    const float bb2 = b2[0];
#pragma unroll
    for (int i = 0; i < 4; ++i) {
        float p = 0.0f;
#pragma unroll
        for (int j = 0; j < 4; ++j) {
            const int c0 = tx * 4 + j;
            const int c1 = 64 + tx * 4 + j;
            const float h0 = acc[i][j] + b1[c0];
            const float h1 = acc[i][4 + j] + b1[c1];
            p += gelu_exact(h0) * W2[c0] + gelu_exact(h1) * W2[c1];
        }
#pragma unroll
        for (int o = 1; o < 16; o <<= 1) p += __shfl_xor(p, o, 64);
        if (tx == 0) scores[rowBase + ty * 4 + i] = p + bb2;
    }
}

// ---------------- Kernel 2: per-batch radix-select top-1024 + stable compact -
__device__ __forceinline__ unsigned sortable_u32(float f) {
    unsigned u = __float_as_uint(f);
    return (u & 0x80000000u) ? ~u : (u | 0x80000000u);  // ascending order
}

__global__ __launch_bounds__(1024)
void select_kernel(const float* __restrict__ scores, int* __restrict__ idx_out,
                   float* __restrict__ out_tail) {
    const int b = blockIdx.x;
    const int t = threadIdx.x;

    __shared__ unsigned hist[256];
    __shared__ unsigned wsum[16];
    __shared__ unsigned s_bin, s_sub;

    // load 8 contiguous scores per thread (index order = scan order)
    unsigned key[8];
    {
        const float* sc = scores + b * SEQ + t * 8;
        float4 v0 = *(const float4*)(sc);
        float4 v1 = *(const float4*)(sc + 4);
        key[0] = sortable_u32(v0.x); key[1] = sortable_u32(v0.y);
        key[2] = sortable_u32(v0.z); key[3] = sortable_u32(v0.w);
        key[4] = sortable_u32(v1.x); key[5] = sortable_u32(v1.y);
        key[6] = sortable_u32(v1.z); key[7] = sortable_u32(v1.w);
    }

    unsigned prefix = 0, need = KEEP;
    for (int r = 0; r < 4; ++r) {
        const int shift = 24 - 8 * r;
        const unsigned mask_hi = (r == 0) ? 0u : (0xFFFFFFFFu << (shift + 8));
        if (t < 256) hist[t] = 0;
        __syncthreads();
#pragma unroll
        for (int j = 0; j < 8; ++j) {
            if ((key[j] & mask_hi) == prefix)
                atomicAdd(&hist[(key[j] >> shift) & 255u], 1u);
        }
        __syncthreads();
        // inclusive suffix scan of hist
        for (int d = 1; d < 256; d <<= 1) {
            unsigned v = 0;
            if (t < 256) { v = hist[t]; if (t + d < 256) v += hist[t + d]; }
            __syncthreads();
            if (t < 256) hist[t] = v;
            __syncthreads();
        }
        if (t < 256) {
            const unsigned S = hist[t];
            const unsigned Sn = (t < 255) ? hist[t + 1] : 0u;
            if (Sn < need && need <= S) { s_bin = (unsigned)t; s_sub = Sn; }
        }
        __syncthreads();
        prefix |= (s_bin << shift);
        need -= s_sub;
        __syncthreads();
    }
    const unsigned tau = prefix;   // value of the 1024th-largest key
    const unsigned m = need;       // #ties (==tau) to keep, lowest-index first

    // packed (gt<<16 | eq) stable scan in index order
    unsigned pk[8], tsum = 0;
#pragma unroll
    for (int j = 0; j < 8; ++j) {
        const unsigned gt = (key[j] > tau) ? 1u : 0u;
        const unsigned eq = (key[j] == tau) ? 1u : 0u;
        pk[j] = tsum;
        tsum += (gt << 16) | eq;
    }
    // wave inclusive scan
    const unsigned lane = t & 63;
    unsigned incl = tsum;
#pragma unroll
    for (int d = 1; d < 64; d <<= 1) {
        const unsigned v = __shfl_up(incl, d, 64);
        if (lane >= d) incl += v;
    }
    if (lane == 63) wsum[t >> 6] = incl;
    __syncthreads();
    if (t == 0) {
        unsigned run = 0;
        for (int w = 0; w < 16; ++w) { const unsigned tmp = wsum[w]; wsum[w] = run; run += tmp; }
    }
    __syncthreads();
    const unsigned base = wsum[t >> 6] + (incl - tsum);

#pragma unroll
    for (int j = 0; j < 8; ++j) {
        const unsigned before = base + pk[j];
        const unsigned gt_before = before >> 16;
        const unsigned eq_before = before & 0xFFFFu;
        const bool keep = (key[j] > tau) || (key[j] == tau && eq_before < m);
        if (keep) {
            const unsigned pos = gt_before + (eq_before < m ? eq_before : m);
            const int idx = t * 8 + j;
            idx_out[b * KEEP + pos] = idx;
            out_tail[b * KEEP + pos] = (float)idx;
        }
    }
}

// ---------------- Kernel 3: gather kept tokens --------------------------------
__global__ __launch_bounds__(256)
void gather_kernel(const float* __restrict__ x, const int* __restrict__ idx,
                   float* __restrict__ out) {
    const int j = blockIdx.x;          // 0..4095 = b*1024 + pos
    const int b = j >> 10;
    const int id = idx[j];
    const float4* src = (const float4*)(x + ((long)b * SEQ + id) * DIMD);
    float4* dst = (float4*)(out + (long)j * DIMD);
    dst[threadIdx.x] = src[threadIdx.x];
}

extern "C" void kernel_launch(void* const* d_in, const int* in_sizes, int n_in,
                              void* d_out, int out_size, void* d_ws, size_t ws_size,
                              hipStream_t stream) {
    const float* x  = (const float*)d_in[0];
    const float* W1 = (const float*)d_in[1];
    const float* b1 = (const float*)d_in[2];
    const float* W2 = (const float*)d_in[3];
    const float* b2 = (const float*)d_in[4];
    float* out = (float*)d_out;

    float* scores = (float*)d_ws;                               // 32768 f32
    int*   idxbuf = (int*)((char*)d_ws + 32768 * sizeof(float)); // 4096 i32

    score_kernel<<<(BATCH * SEQ) / BM, 256, 0, stream>>>(x, W1, b1, W2, b2, scores);
    select_kernel<<<BATCH, 1024, 0, stream>>>(scores, idxbuf,
                                              out + (long)BATCH * KEEP * DIMD);
    gather_kernel<<<BATCH * KEEP, 256, 0, stream>>>(x, idxbuf, out);
}

// Round 4
// 241.038 us; speedup vs baseline: 1.1980x; 1.1980x over previous
//
#include <hip/hip_runtime.h>
#include <hip/hip_bf16.h>

#define DIMD 1024
#define HIDD 128
#define SEQ  8192
#define BATCH 4
#define KEEP 1024

typedef __attribute__((ext_vector_type(8))) short short8;
typedef __attribute__((ext_vector_type(4))) float f32x4;
typedef __attribute__((ext_vector_type(4))) unsigned int u32x4;

__device__ __forceinline__ unsigned short f2bf(float f) {   // RNE f32->bf16
    unsigned u = __float_as_uint(f);
    u += 0x7FFFu + ((u >> 16) & 1u);
    return (unsigned short)(u >> 16);
}
__device__ __forceinline__ float bf2f(unsigned short h) {
    return __uint_as_float((unsigned)h << 16);
}
__device__ __forceinline__ float gelu_exact(float h) {
    return 0.5f * h * (1.0f + erff(h * 0.70710678118654752440f));
}
__device__ __forceinline__ void gload_lds16(const void* g, void* l) {
    __builtin_amdgcn_global_load_lds(
        (const __attribute__((address_space(1))) void*)g,
        (__attribute__((address_space(3))) void*)l, 16, 0, 0);
}

// ---------- Kernel 0: split W1 into 3 bf16 limbs, written as pre-swizzled ----
// LDS tile images: img[limb][kt][ col*128 + ((kl*2) ^ ((col&7)<<4)) ]
__global__ __launch_bounds__(256)
void w1split_kernel(const float* __restrict__ W1, char* __restrict__ img) {
    const int t = blockIdx.x * 256 + threadIdx.x;   // 16384 = 128c * 8j * 16kt
    const int c = t & 127;
    const int j = (t >> 7) & 7;
    const int kt = t >> 10;
    u32x4 ph, pm, pl;
    unsigned short hs[8], ms[8], ls[8];
#pragma unroll
    for (int i = 0; i < 8; ++i) {
        const float f = W1[(kt * 64 + j * 8 + i) * 128 + c];  // W1 is [k][c]
        const unsigned short h = f2bf(f);  const float r1 = f - bf2f(h);
        const unsigned short m = f2bf(r1); const float r2 = r1 - bf2f(m);
        const unsigned short l = f2bf(r2);
        hs[i] = h; ms[i] = m; ls[i] = l;
    }
#pragma unroll
    for (int p = 0; p < 4; ++p) {
        ph[p] = (unsigned)hs[2 * p] | ((unsigned)hs[2 * p + 1] << 16);
        pm[p] = (unsigned)ms[2 * p] | ((unsigned)ms[2 * p + 1] << 16);
        pl[p] = (unsigned)ls[2 * p] | ((unsigned)ls[2 * p + 1] << 16);
    }
    const int off = kt * 16384 + c * 128 + 16 * (j ^ (c & 7));
    *(u32x4*)(img + 0 * 262144 + off) = ph;
    *(u32x4*)(img + 1 * 262144 + off) = pm;
    *(u32x4*)(img + 2 * 262144 + off) = pl;
}

// ---------- Kernel 1: MFMA scorer, 3-limb split, 6 product terms -------------
// BM=64 rows/block, BN=128 (full H), BK=64. 4 waves in 2x2 (wm,wn) grid.
__global__ __launch_bounds__(256, 2)
void score_mfma(const float* __restrict__ x, const char* __restrict__ w1img,
                const float* __restrict__ b1, const float* __restrict__ W2,
                const float* __restrict__ b2, float* __restrict__ scores) {
    __shared__ __align__(16) char lds[73728];
    char* const Abuf[3] = { lds, lds + 8192, lds + 16384 };       // [64][128B]
    char* const Bbuf[3] = { lds + 24576, lds + 40960, lds + 57344 }; // [128][128B]

    const int tid = threadIdx.x;
    const int lane = tid & 63;
    const int wid = tid >> 6;
    const int wm = wid >> 1;     // row half (32 rows)
    const int wn = wid & 1;      // col half (64 cols)
    const long rowBase = (long)blockIdx.x * 64;

    f32x4 acc[2][4];
#pragma unroll
    for (int m = 0; m < 2; ++m)
#pragma unroll
        for (int n = 0; n < 4; ++n) acc[m][n] = (f32x4){0.f, 0.f, 0.f, 0.f};

    for (int kt = 0; kt < DIMD; kt += 64) {
        __syncthreads();  // protect LDS reads of previous chunk
        {   // stage B: async flat copy of pre-swizzled 16KB tile images x3 limbs
            const long tbase = (long)(kt >> 6) * 16384;
#pragma unroll
            for (int limb = 0; limb < 3; ++limb)
#pragma unroll
                for (int i = 0; i < 4; ++i) {
                    const int off = wid * 4096 + i * 1024;
                    gload_lds16(w1img + (long)limb * 262144 + tbase + off + lane * 16,
                                Bbuf[limb] + off);
                }
        }
        {   // stage A: 16 floats/thread -> 3 bf16 limbs, swizzled LDS writes
            const int row = tid >> 2, q = tid & 3;
            const float* gx = x + (rowBase + row) * DIMD + kt + q * 16;
#pragma unroll
            for (int j = 0; j < 2; ++j) {
                const f32x4 v0 = *(const f32x4*)(gx + j * 8);
                const f32x4 v1 = *(const f32x4*)(gx + j * 8 + 4);
                float va[8];
#pragma unroll
                for (int i = 0; i < 4; ++i) { va[i] = v0[i]; va[4 + i] = v1[i]; }
                u32x4 qh, qm, ql;
#pragma unroll
                for (int p = 0; p < 4; ++p) {
                    const float f0 = va[2 * p], f1 = va[2 * p + 1];
                    const unsigned short h0 = f2bf(f0);  const float r10 = f0 - bf2f(h0);
                    const unsigned short m0 = f2bf(r10); const float r20 = r10 - bf2f(m0);
                    const unsigned short l0 = f2bf(r20);
                    const unsigned short h1 = f2bf(f1);  const float r11 = f1 - bf2f(h1);
                    const unsigned short m1 = f2bf(r11); const float r21 = r11 - bf2f(m1);
                    const unsigned short l1 = f2bf(r21);
                    qh[p] = (unsigned)h0 | ((unsigned)h1 << 16);
                    qm[p] = (unsigned)m0 | ((unsigned)m1 << 16);
                    ql[p] = (unsigned)l0 | ((unsigned)l1 << 16);
                }
                const int kb = q * 32 + j * 16;
                const int off = row * 128 + (kb ^ ((row & 7) << 4));
                *(u32x4*)(Abuf[0] + off) = qh;
                *(u32x4*)(Abuf[1] + off) = qm;
                *(u32x4*)(Abuf[2] + off) = ql;
            }
        }
        __syncthreads();  // drains vmcnt (global_load_lds) + lgkmcnt

#pragma unroll
        for (int ks = 0; ks < 2; ++ks) {
            const int kbase = ks * 64 + (lane >> 4) * 16;   // K=32 per MFMA -> 64B per step
            short8 bh[4], bm[4], bl[4];
#pragma unroll
            for (int n = 0; n < 4; ++n) {
                const int col = wn * 64 + n * 16 + (lane & 15);
                const int off = col * 128 + (kbase ^ ((col & 7) << 4));
                bh[n] = *(const short8*)(Bbuf[0] + off);
                bm[n] = *(const short8*)(Bbuf[1] + off);
                bl[n] = *(const short8*)(Bbuf[2] + off);
            }
#pragma unroll
            for (int m = 0; m < 2; ++m) {
                const int row = wm * 32 + m * 16 + (lane & 15);
                const int off = row * 128 + (kbase ^ ((row & 7) << 4));
                const short8 ah = *(const short8*)(Abuf[0] + off);
                const short8 am = *(const short8*)(Abuf[1] + off);
                const short8 al = *(const short8*)(Abuf[2] + off);
#pragma unroll
                for (int n = 0; n < 4; ++n) {
                    acc[m][n] = __builtin_amdgcn_mfma_f32_16x16x32_bf16(ah, bh[n], acc[m][n], 0, 0, 0);
                    acc[m][n] = __builtin_amdgcn_mfma_f32_16x16x32_bf16(ah, bm[n], acc[m][n], 0, 0, 0);
                    acc[m][n] = __builtin_amdgcn_mfma_f32_16x16x32_bf16(am, bh[n], acc[m][n], 0, 0, 0);
                    acc[m][n] = __builtin_amdgcn_mfma_f32_16x16x32_bf16(am, bm[n], acc[m][n], 0, 0, 0);
                    acc[m][n] = __builtin_amdgcn_mfma_f32_16x16x32_bf16(ah, bl[n], acc[m][n], 0, 0, 0);
                    acc[m][n] = __builtin_amdgcn_mfma_f32_16x16x32_bf16(al, bh[n], acc[m][n], 0, 0, 0);
                }
            }
        }
    }

    // epilogue: h = acc + b1[col]; p = gelu(h)*W2[col]; row-sum over 128 cols
    float rsum[2][4];
#pragma unroll
    for (int m = 0; m < 2; ++m)
#pragma unroll
        for (int r = 0; r < 4; ++r) rsum[m][r] = 0.f;
#pragma unroll
    for (int n = 0; n < 4; ++n) {
        const int col = wn * 64 + n * 16 + (lane & 15);
        const float b1c = b1[col], w2c = W2[col];
#pragma unroll
        for (int m = 0; m < 2; ++m)
#pragma unroll
            for (int r = 0; r < 4; ++r)
                rsum[m][r] += gelu_exact(acc[m][n][r] + b1c) * w2c;
    }
#pragma unroll
    for (int m = 0; m < 2; ++m)
#pragma unroll
        for (int r = 0; r < 4; ++r) {
#pragma unroll
            for (int o = 1; o < 16; o <<= 1)
                rsum[m][r] += __shfl_xor(rsum[m][r], o, 64);
        }
    __syncthreads();                       // done reading tiles; reuse LDS
    float* scpad = (float*)lds;            // [2 halves][64 rows]
    if ((lane & 15) == 0) {
#pragma unroll
        for (int m = 0; m < 2; ++m)
#pragma unroll
            for (int r = 0; r < 4; ++r) {
                const int row = wm * 32 + m * 16 + (lane >> 4) * 4 + r;
                scpad[wn * 64 + row] = rsum[m][r];
            }
    }
    __syncthreads();
    if (tid < 64)
        scores[rowBase + tid] = scpad[tid] + scpad[64 + tid] + b2[0];
}

// ---------- Kernel 2: per-batch radix-select top-1024 + stable compact -------
__device__ __forceinline__ unsigned sortable_u32(float f) {
    unsigned u = __float_as_uint(f);
    return (u & 0x80000000u) ? ~u : (u | 0x80000000u);
}

__global__ __launch_bounds__(1024)
void select_kernel(const float* __restrict__ scores, int* __restrict__ idx_out,
                   float* __restrict__ out_tail) {
    const int b = blockIdx.x;
    const int t = threadIdx.x;
    const int wave = t >> 6, lane = t & 63;

    __shared__ unsigned wh[16 * 256];
    __shared__ unsigned wsum[16];
    __shared__ unsigned sbc_bin, sbc_sub;

    unsigned key[8];
    {
        const float* sc = scores + b * SEQ + t * 8;
        f32x4 v0 = *(const f32x4*)(sc);
        f32x4 v1 = *(const f32x4*)(sc + 4);
#pragma unroll
        for (int i = 0; i < 4; ++i) {
            key[i] = sortable_u32(v0[i]);
            key[4 + i] = sortable_u32(v1[i]);
        }
    }

    unsigned prefix = 0, need = KEEP;
    for (int r = 0; r < 4; ++r) {
        const int shift = 24 - 8 * r;
        const unsigned mask_hi = (r == 0) ? 0u : (0xFFFFFFFFu << (shift + 8));
#pragma unroll
        for (int i = 0; i < 4; ++i) wh[t + i * 1024] = 0;
        __syncthreads();
#pragma unroll
        for (int j = 0; j < 8; ++j)
            if ((key[j] & mask_hi) == prefix)
                atomicAdd(&wh[wave * 256 + ((key[j] >> shift) & 255u)], 1u);
        __syncthreads();
        if (t < 256) {
            unsigned s = 0;
#pragma unroll
            for (int w = 0; w < 16; ++w) s += wh[w * 256 + t];
            wh[t] = s;
        }
        __syncthreads();
        if (wave == 0) {
            const unsigned h0 = wh[lane * 4 + 0], h1 = wh[lane * 4 + 1];
            const unsigned h2 = wh[lane * 4 + 2], h3 = wh[lane * 4 + 3];
            const unsigned s3 = h3, s2 = h2 + s3, s1 = h1 + s2, s0 = h0 + s1;
            unsigned run = s0;
#pragma unroll
            for (int d = 1; d < 64; d <<= 1) {
                const unsigned v = __shfl_down(run, d, 64);
                if (lane + d < 64) run += v;
            }
            const unsigned above = run - s0;            // suffix of bin 4(lane+1)
            const unsigned suf0 = above + s0, suf1 = above + s1;
            const unsigned suf2 = above + s2, suf3 = above + s3;
            if (suf1 < need && need <= suf0) { sbc_bin = lane * 4 + 0; sbc_sub = suf1; }
            if (suf2 < need && need <= suf1) { sbc_bin = lane * 4 + 1; sbc_sub = suf2; }
            if (suf3 < need && need <= suf2) { sbc_bin = lane * 4 + 2; sbc_sub = suf3; }
            if (above < need && need <= suf3) { sbc_bin = lane * 4 + 3; sbc_sub = above; }
        }
        __syncthreads();
        prefix |= sbc_bin << shift;
        need -= sbc_sub;
        __syncthreads();
    }
    const unsigned tau = prefix;   // key value of the 1024th-largest
    const unsigned m = need;       // #ties (==tau) to keep, lowest-index first

    // packed (gt<<16 | eq) stable scan in index order (verified round 1)
    unsigned pk[8], tsum = 0;
#pragma unroll
    for (int j = 0; j < 8; ++j) {
        const unsigned gt = (key[j] > tau) ? 1u : 0u;
        const unsigned eq = (key[j] == tau) ? 1u : 0u;
        pk[j] = tsum;
        tsum += (gt << 16) | eq;
    }
    unsigned incl = tsum;
#pragma unroll
    for (int d = 1; d < 64; d <<= 1) {
        const unsigned v = __shfl_up(incl, d, 64);
        if (lane >= d) incl += v;
    }
    if (lane == 63) wsum[wave] = incl;
    __syncthreads();
    if (t == 0) {
        unsigned run = 0;
        for (int w = 0; w < 16; ++w) { const unsigned tmp = wsum[w]; wsum[w] = run; run += tmp; }
    }
    __syncthreads();
    const unsigned base = wsum[wave] + (incl - tsum);

#pragma unroll
    for (int j = 0; j < 8; ++j) {
        const unsigned before = base + pk[j];
        const unsigned gt_before = before >> 16;
        const unsigned eq_before = before & 0xFFFFu;
        const bool keep = (key[j] > tau) || (key[j] == tau && eq_before < m);
        if (keep) {
            const unsigned pos = gt_before + (eq_before < m ? eq_before : m);
            const int idx = t * 8 + j;
            idx_out[b * KEEP + pos] = idx;
            out_tail[b * KEEP + pos] = (float)idx;
        }
    }
}

// ---------- Kernel 3: gather kept tokens -------------------------------------
__global__ __launch_bounds__(256)
void gather_kernel(const float* __restrict__ x, const int* __restrict__ idx,
                   float* __restrict__ out) {
    const int j = blockIdx.x;          // 0..4095 = b*1024 + pos
    const int b = j >> 10;
    const int id = idx[j];
    const f32x4* src = (const f32x4*)(x + ((long)b * SEQ + id) * DIMD);
    f32x4* dst = (f32x4*)(out + (long)j * DIMD);
    dst[threadIdx.x] = src[threadIdx.x];
}

extern "C" void kernel_launch(void* const* d_in, const int* in_sizes, int n_in,
                              void* d_out, int out_size, void* d_ws, size_t ws_size,
                              hipStream_t stream) {
    const float* x  = (const float*)d_in[0];
    const float* W1 = (const float*)d_in[1];
    const float* b1 = (const float*)d_in[2];
    const float* W2 = (const float*)d_in[3];
    const float* b2 = (const float*)d_in[4];
    float* out = (float*)d_out;

    char* ws = (char*)d_ws;
    char*  w1img  = ws;                               // 3 x 256KB limb images
    float* scores = (float*)(ws + 786432);            // 128KB
    int*   idxbuf = (int*)(ws + 786432 + 131072);     // 16KB

    w1split_kernel<<<64, 256, 0, stream>>>(W1, w1img);
    score_mfma<<<(BATCH * SEQ) / 64, 256, 0, stream>>>(x, w1img, b1, W2, b2, scores);
    select_kernel<<<BATCH, 1024, 0, stream>>>(scores, idxbuf,
                                              out + (long)BATCH * KEEP * DIMD);
    gather_kernel<<<BATCH * KEEP, 256, 0, stream>>>(x, idxbuf, out);
}

// Round 5
// 229.718 us; speedup vs baseline: 1.2571x; 1.0493x over previous
//
#include <hip/hip_runtime.h>
#include <hip/hip_bf16.h>

#define DIMD 1024
#define HIDD 128
#define SEQ  8192
#define BATCH 4
#define KEEP 1024

typedef __attribute__((ext_vector_type(8))) short short8;
typedef __attribute__((ext_vector_type(8))) _Float16 f16x8;
typedef __attribute__((ext_vector_type(4))) float f32x4;
typedef __attribute__((ext_vector_type(4))) unsigned int u32x4;

__device__ __forceinline__ float gelu_exact(float h) {
    return 0.5f * h * (1.0f + erff(h * 0.70710678118654752440f));
}
__device__ __forceinline__ void gload_lds16(const void* g, void* l) {
    __builtin_amdgcn_global_load_lds(
        (const __attribute__((address_space(1))) void*)g,
        (__attribute__((address_space(3))) void*)l, 16, 0, 0);
}

// ---------- Kernel 0: split W1 into 2 f16 limbs (lo pre-scaled by 2^12), -----
// written as pre-swizzled LDS tile images: img[limb][kt][c*128 + 16*(j^(c&7))]
__global__ __launch_bounds__(256)
void w1split_kernel(const float* __restrict__ W1, char* __restrict__ img) {
    const int t = blockIdx.x * 256 + threadIdx.x;   // 16384 = 128c * 8j * 16kt
    const int c = t & 127;
    const int j = (t >> 7) & 7;
    const int kt = t >> 10;
    f16x8 hv, lv;
#pragma unroll
    for (int i = 0; i < 8; ++i) {
        const float f = W1[(kt * 64 + j * 8 + i) * 128 + c];  // W1 is [k][c]
        const _Float16 h = (_Float16)f;
        const _Float16 l = (_Float16)((f - (float)h) * 4096.0f);
        hv[i] = h; lv[i] = l;
    }
    const int off = kt * 16384 + c * 128 + 16 * (j ^ (c & 7));
    *(f16x8*)(img + off) = hv;
    *(f16x8*)(img + 262144 + off) = lv;
}

// ---------- Kernel 1: MFMA scorer, f16 2-limb split, 3 product terms ---------
// BM=64 rows/block, BN=128 (full H), BK=64. 4 waves in 2x2 (wm,wn) grid.
// LDS 48KB -> 3 blocks/CU.
__global__ __launch_bounds__(256, 3)
void score_mfma(const float* __restrict__ x, const char* __restrict__ w1img,
                const float* __restrict__ b1, const float* __restrict__ W2,
                const float* __restrict__ b2, float* __restrict__ scores) {
    __shared__ __align__(16) char lds[49152];
    char* const Ah = lds;            // [64 rows][128B] f16 hi, swizzled
    char* const Al = lds + 8192;     // lo (pre-scaled 2^12)
    char* const Bh = lds + 16384;    // [128 cols][128B]
    char* const Bl = lds + 32768;

    const int tid = threadIdx.x;
    const int lane = tid & 63;
    const int wid = tid >> 6;
    const int wm = wid >> 1;     // row half (32 rows)
    const int wn = wid & 1;      // col half (64 cols)
    const long rowBase = (long)blockIdx.x * 64;

    f32x4 acc[2][4], acc2[2][4];
#pragma unroll
    for (int m = 0; m < 2; ++m)
#pragma unroll
        for (int n = 0; n < 4; ++n) {
            acc[m][n] = (f32x4){0.f, 0.f, 0.f, 0.f};
            acc2[m][n] = (f32x4){0.f, 0.f, 0.f, 0.f};
        }

    for (int kt = 0; kt < DIMD; kt += 64) {
        __syncthreads();  // protect LDS reads of previous chunk
        {   // stage B: async flat copy of pre-swizzled 16KB tile images x2 limbs
            const long tbase = (long)(kt >> 6) * 16384;
#pragma unroll
            for (int i = 0; i < 4; ++i) {
                const int off = wid * 4096 + i * 1024;
                gload_lds16(w1img + tbase + off + lane * 16, Bh + off);
                gload_lds16(w1img + 262144 + tbase + off + lane * 16, Bl + off);
            }
        }
        {   // stage A: 16 floats/thread -> 2 f16 limbs, swizzled LDS writes
            const int row = tid >> 2, q = tid & 3;
            const float* gx = x + (rowBase + row) * DIMD + kt + q * 16;
#pragma unroll
            for (int j = 0; j < 2; ++j) {
                const f32x4 v0 = *(const f32x4*)(gx + j * 8);
                const f32x4 v1 = *(const f32x4*)(gx + j * 8 + 4);
                f16x8 hv, lv;
#pragma unroll
                for (int i = 0; i < 4; ++i) {
                    const _Float16 h0 = (_Float16)v0[i];
                    const _Float16 h1 = (_Float16)v1[i];
                    hv[i] = h0; hv[4 + i] = h1;
                    lv[i] = (_Float16)((v0[i] - (float)h0) * 4096.0f);
                    lv[4 + i] = (_Float16)((v1[i] - (float)h1) * 4096.0f);
                }
                const int kb = q * 32 + j * 16;
                const int off = row * 128 + (kb ^ ((row & 7) << 4));
                *(f16x8*)(Ah + off) = hv;
                *(f16x8*)(Al + off) = lv;
            }
        }
        __syncthreads();  // drains vmcnt (global_load_lds) + lgkmcnt

#pragma unroll
        for (int ks = 0; ks < 2; ++ks) {
            const int kbase = ks * 64 + (lane >> 4) * 16;   // K=32 per MFMA = 64B
            f16x8 ah[2], al[2];
#pragma unroll
            for (int m = 0; m < 2; ++m) {
                const int row = wm * 32 + m * 16 + (lane & 15);
                const int off = row * 128 + (kbase ^ ((row & 7) << 4));
                ah[m] = *(const f16x8*)(Ah + off);
                al[m] = *(const f16x8*)(Al + off);
            }
#pragma unroll
            for (int n = 0; n < 4; ++n) {
                const int col = wn * 64 + n * 16 + (lane & 15);
                const int off = col * 128 + (kbase ^ ((col & 7) << 4));
                const f16x8 bh = *(const f16x8*)(Bh + off);
                const f16x8 bl = *(const f16x8*)(Bl + off);
#pragma unroll
                for (int m = 0; m < 2; ++m) {
                    acc[m][n]  = __builtin_amdgcn_mfma_f32_16x16x32_f16(ah[m], bh, acc[m][n], 0, 0, 0);
                    acc2[m][n] = __builtin_amdgcn_mfma_f32_16x16x32_f16(ah[m], bl, acc2[m][n], 0, 0, 0);
                    acc2[m][n] = __builtin_amdgcn_mfma_f32_16x16x32_f16(al[m], bh, acc2[m][n], 0, 0, 0);
                }
            }
        }
    }

    // epilogue: h = acc + 2^-12*acc2 + b1[col]; p = gelu(h)*W2[col]; row-sum
    float rsum[2][4];
#pragma unroll
    for (int m = 0; m < 2; ++m)
#pragma unroll
        for (int r = 0; r < 4; ++r) rsum[m][r] = 0.f;
#pragma unroll
    for (int n = 0; n < 4; ++n) {
        const int col = wn * 64 + n * 16 + (lane & 15);
        const float b1c = b1[col], w2c = W2[col];
#pragma unroll
        for (int m = 0; m < 2; ++m)
#pragma unroll
            for (int r = 0; r < 4; ++r) {
                const float h = acc[m][n][r] + 2.44140625e-4f * acc2[m][n][r] + b1c;
                rsum[m][r] += gelu_exact(h) * w2c;
            }
    }
#pragma unroll
    for (int m = 0; m < 2; ++m)
#pragma unroll
        for (int r = 0; r < 4; ++r) {
#pragma unroll
            for (int o = 1; o < 16; o <<= 1)
                rsum[m][r] += __shfl_xor(rsum[m][r], o, 64);
        }
    __syncthreads();                       // done reading tiles; reuse LDS
    float* scpad = (float*)lds;            // [2 halves][64 rows]
    if ((lane & 15) == 0) {
#pragma unroll
        for (int m = 0; m < 2; ++m)
#pragma unroll
            for (int r = 0; r < 4; ++r) {
                const int row = wm * 32 + m * 16 + (lane >> 4) * 4 + r;
                scpad[wn * 64 + row] = rsum[m][r];
            }
    }
    __syncthreads();
    if (tid < 64)
        scores[rowBase + tid] = scpad[tid] + scpad[64 + tid] + b2[0];
}

// ---------- Kernel 2: per-batch radix-select top-1024 + stable compact -------
__device__ __forceinline__ unsigned sortable_u32(float f) {
    unsigned u = __float_as_uint(f);
    return (u & 0x80000000u) ? ~u : (u | 0x80000000u);
}

__global__ __launch_bounds__(1024)
void select_kernel(const float* __restrict__ scores, int* __restrict__ idx_out,
                   float* __restrict__ out_tail) {
    const int b = blockIdx.x;
    const int t = threadIdx.x;
    const int wave = t >> 6, lane = t & 63;

    __shared__ unsigned wh[16 * 256];
    __shared__ unsigned wsum[16];
    __shared__ unsigned sbc_bin, sbc_sub;

    unsigned key[8];
    {
        const float* sc = scores + b * SEQ + t * 8;
        f32x4 v0 = *(const f32x4*)(sc);
        f32x4 v1 = *(const f32x4*)(sc + 4);
#pragma unroll
        for (int i = 0; i < 4; ++i) {
            key[i] = sortable_u32(v0[i]);
            key[4 + i] = sortable_u32(v1[i]);
        }
    }

    unsigned prefix = 0, need = KEEP;
    for (int r = 0; r < 4; ++r) {
        const int shift = 24 - 8 * r;
        const unsigned mask_hi = (r == 0) ? 0u : (0xFFFFFFFFu << (shift + 8));
#pragma unroll
        for (int i = 0; i < 4; ++i) wh[t + i * 1024] = 0;
        __syncthreads();
#pragma unroll
        for (int j = 0; j < 8; ++j)
            if ((key[j] & mask_hi) == prefix)
                atomicAdd(&wh[wave * 256 + ((key[j] >> shift) & 255u)], 1u);
        __syncthreads();
        if (t < 256) {
            unsigned s = 0;
#pragma unroll
            for (int w = 0; w < 16; ++w) s += wh[w * 256 + t];
            wh[t] = s;
        }
        __syncthreads();
        if (wave == 0) {
            const unsigned h0 = wh[lane * 4 + 0], h1 = wh[lane * 4 + 1];
            const unsigned h2 = wh[lane * 4 + 2], h3 = wh[lane * 4 + 3];
            const unsigned s3 = h3, s2 = h2 + s3, s1 = h1 + s2, s0 = h0 + s1;
            unsigned run = s0;
#pragma unroll
            for (int d = 1; d < 64; d <<= 1) {
                const unsigned v = __shfl_down(run, d, 64);
                if (lane + d < 64) run += v;
            }
            const unsigned above = run - s0;            // suffix of bin 4(lane+1)
            const unsigned suf0 = above + s0, suf1 = above + s1;
            const unsigned suf2 = above + s2, suf3 = above + s3;
            if (suf1 < need && need <= suf0) { sbc_bin = lane * 4 + 0; sbc_sub = suf1; }
            if (suf2 < need && need <= suf1) { sbc_bin = lane * 4 + 1; sbc_sub = suf2; }
            if (suf3 < need && need <= suf2) { sbc_bin = lane * 4 + 2; sbc_sub = suf3; }
            if (above < need && need <= suf3) { sbc_bin = lane * 4 + 3; sbc_sub = above; }
        }
        __syncthreads();
        prefix |= sbc_bin << shift;
        need -= sbc_sub;
        __syncthreads();
    }
    const unsigned tau = prefix;   // key value of the 1024th-largest
    const unsigned m = need;       // #ties (==tau) to keep, lowest-index first

    // packed (gt<<16 | eq) stable scan in index order (verified round 1/4)
    unsigned pk[8], tsum = 0;
#pragma unroll
    for (int j = 0; j < 8; ++j) {
        const unsigned gt = (key[j] > tau) ? 1u : 0u;
        const unsigned eq = (key[j] == tau) ? 1u : 0u;
        pk[j] = tsum;
        tsum += (gt << 16) | eq;
    }
    unsigned incl = tsum;
#pragma unroll
    for (int d = 1; d < 64; d <<= 1) {
        const unsigned v = __shfl_up(incl, d, 64);
        if (lane >= d) incl += v;
    }
    if (lane == 63) wsum[wave] = incl;
    __syncthreads();
    if (t == 0) {
        unsigned run = 0;
        for (int w = 0; w < 16; ++w) { const unsigned tmp = wsum[w]; wsum[w] = run; run += tmp; }
    }
    __syncthreads();
    const unsigned base = wsum[wave] + (incl - tsum);

#pragma unroll
    for (int j = 0; j < 8; ++j) {
        const unsigned before = base + pk[j];
        const unsigned gt_before = before >> 16;
        const unsigned eq_before = before & 0xFFFFu;
        const bool keep = (key[j] > tau) || (key[j] == tau && eq_before < m);
        if (keep) {
            const unsigned pos = gt_before + (eq_before < m ? eq_before : m);
            const int idx = t * 8 + j;
            idx_out[b * KEEP + pos] = idx;
            out_tail[b * KEEP + pos] = (float)idx;
        }
    }
}

// ---------- Kernel 3: gather kept tokens -------------------------------------
__global__ __launch_bounds__(256)
void gather_kernel(const float* __restrict__ x, const int* __restrict__ idx,
                   float* __restrict__ out) {
    const int j = blockIdx.x;          // 0..4095 = b*1024 + pos
    const int b = j >> 10;
    const int id = idx[j];
    const f32x4* src = (const f32x4*)(x + ((long)b * SEQ + id) * DIMD);
    f32x4* dst = (f32x4*)(out + (long)j * DIMD);
    dst[threadIdx.x] = src[threadIdx.x];
}

extern "C" void kernel_launch(void* const* d_in, const int* in_sizes, int n_in,
                              void* d_out, int out_size, void* d_ws, size_t ws_size,
                              hipStream_t stream) {
    const float* x  = (const float*)d_in[0];
    const float* W1 = (const float*)d_in[1];
    const float* b1 = (const float*)d_in[2];
    const float* W2 = (const float*)d_in[3];
    const float* b2 = (const float*)d_in[4];
    float* out = (float*)d_out;

    char* ws = (char*)d_ws;
    char*  w1img  = ws;                               // 2 x 256KB limb images
    float* scores = (float*)(ws + 524288);            // 128KB
    int*   idxbuf = (int*)(ws + 524288 + 131072);     // 16KB

    w1split_kernel<<<64, 256, 0, stream>>>(W1, w1img);
    score_mfma<<<(BATCH * SEQ) / 64, 256, 0, stream>>>(x, w1img, b1, W2, b2, scores);
    select_kernel<<<BATCH, 1024, 0, stream>>>(scores, idxbuf,
                                              out + (long)BATCH * KEEP * DIMD);
    gather_kernel<<<BATCH * KEEP, 256, 0, stream>>>(x, idxbuf, out);
}